// Round 3
// baseline (8360.025 us; speedup 1.0000x reference)
//
#include <hip/hip_runtime.h>
#include <hip/hip_bf16.h>

#define B_   8
#define T_   12
#define CIN  16
#define HD   96
#define COUT 8
#define CE   112
#define CD   104
#define HW   4096
#define WIMG 64

typedef __hip_bfloat16 bf16;

__device__ __forceinline__ float b2f(bf16 v) { return __bfloat162float(v); }
__device__ __forceinline__ float sigmf_(float x) { return 1.0f / (1.0f + __expf(-x)); }
__device__ __forceinline__ float tanhf_(float x) { return 2.0f / (1.0f + __expf(-2.0f * x)) - 1.0f; }

// load element i of an input tensor whose dtype is decided at runtime
__device__ __forceinline__ float ldin(const void* p, long i, int f32) {
    return f32 ? ((const float*)p)[i] : b2f(((const bf16*)p)[i]);
}

// ---------------------------------------------------------------------------
// detect: decide whether inputs are fp32 or bf16 by inspecting eWf bit
// patterns. bf16 weights ~N(0,0.094^2): exponent field in [90,128] for all 64
// words. fp32 reinterpreted as bf16: even words are mantissa fragments with
// uniform exponent bits -> many fail. flag=1 means fp32.
// ---------------------------------------------------------------------------
__global__ void detect_k(const void* w, int* flag) {
    if (threadIdx.x == 0 && blockIdx.x == 0) {
        const unsigned short* u = (const unsigned short*)w;
        int bad = 0;
        for (int i = 0; i < 64; i++) {
            unsigned short v = u[i];
            unsigned e = (v >> 7) & 0xFF;
            if (!(v == 0 || (e >= 90 && e <= 128))) bad++;
        }
        *flag = (bad > 8) ? 1 : 0;
    }
}

// ---------------------------------------------------------------------------
// prep: convert all recurrent-loop weights (bf16 or fp32) -> fp32 workspace
// ---------------------------------------------------------------------------
__global__ void prep_k(
    const void* p0, const void* p1, const void* p2, const void* p3,
    const void* p4, const void* p5, const void* p6, const void* p7,
    const void* p8, const void* p9, const void* p10, const void* p11,
    const void* p12, const void* p13, const void* p14, const void* p15,
    float* __restrict__ dst, const int* __restrict__ flag)
{
    const int f32 = *flag;
    const void* srcs[16] = {p0,p1,p2,p3,p4,p5,p6,p7,p8,p9,p10,p11,p12,p13,p14,p15};
    const int sizes[16] = {10752,10752,10752,10752, 96,96,96,96,
                           89856,89856,89856, 96,96,96, 9984, 96};
    int i = blockIdx.x * blockDim.x + threadIdx.x;
    float* d = dst;
    #pragma unroll 1
    for (int s = 0; s < 16; s++) {
        if (i < sizes[s]) { d[i] = ldin(srcs[s], i, f32); return; }
        i -= sizes[s];
        d += sizes[s];
    }
}

// ---------------------------------------------------------------------------
// combine: fold output head conv(oK)+ob then linear(lW)+lb into one conv
// K2[(c*9+tap)*8 + o] = sum_cd lW[cd,o]*oK[cd,c,tap]; b2[o] = lb[o]+sum ob*lW
// ---------------------------------------------------------------------------
__global__ void combine_k(const void* __restrict__ oK, const void* __restrict__ obv,
                          const void* __restrict__ lW, const void* __restrict__ lb,
                          float* __restrict__ K2, float* __restrict__ b2,
                          const int* __restrict__ flag)
{
    const int f32 = *flag;
    int i = blockIdx.x * blockDim.x + threadIdx.x;  // over HD*9 = 864 (c,tap)
    if (i < HD * 9) {
        float acc[8] = {0,0,0,0,0,0,0,0};
        for (int cd = 0; cd < CD; cd++) {
            float kv = ldin(oK, cd * (HD * 9) + i, f32);
            #pragma unroll
            for (int o = 0; o < 8; o++)
                acc[o] = fmaf(kv, ldin(lW, cd * COUT + o, f32), acc[o]);
        }
        #pragma unroll
        for (int o = 0; o < 8; o++) K2[i * 8 + o] = acc[o];
    }
    if (i < COUT) {
        float a = ldin(lb, i, f32);
        for (int cd = 0; cd < CD; cd++)
            a = fmaf(ldin(obv, cd, f32), ldin(lW, cd * COUT + i, f32), a);
        b2[i] = a;
    }
}

// ---------------------------------------------------------------------------
// encoder step: 4 fused channel-linears + LSTM update
// grid (16, 24, 8): hw-tile, d-group(4), batch. block 256 over hw.
// ---------------------------------------------------------------------------
__global__ __launch_bounds__(256) void enc_step_k(
    const void* __restrict__ x, int t,
    const float* __restrict__ hin, float* __restrict__ hout, float* __restrict__ cst,
    const float* __restrict__ Wf, const float* __restrict__ Wi,
    const float* __restrict__ Wc, const float* __restrict__ Wo,
    const float* __restrict__ bfv, const float* __restrict__ biv,
    const float* __restrict__ bcv, const float* __restrict__ bov,
    int first, const int* __restrict__ flag)
{
    const int f32 = *flag;
    const int hw = blockIdx.x * 256 + threadIdx.x;
    const int d0 = blockIdx.y * 4;
    const int b  = blockIdx.z;

    const long xoff = ((long)(b * T_ + t) * CIN) * HW + hw;
    const float* hp = hin + (b * HD) * HW + hw;

    float af[4] = {0,0,0,0}, ai[4] = {0,0,0,0}, ag[4] = {0,0,0,0}, ao[4] = {0,0,0,0};

    if (f32) {
        const float* xp = (const float*)x + xoff;
        #pragma unroll 4
        for (int c = 0; c < CIN; c++) {
            float v = xp[c * HW];
            int r = c * HD + d0;
            #pragma unroll
            for (int j = 0; j < 4; j++) {
                af[j] = fmaf(v, Wf[r + j], af[j]);
                ai[j] = fmaf(v, Wi[r + j], ai[j]);
                ag[j] = fmaf(v, Wc[r + j], ag[j]);
                ao[j] = fmaf(v, Wo[r + j], ao[j]);
            }
        }
    } else {
        const bf16* xp = (const bf16*)x + xoff;
        #pragma unroll 4
        for (int c = 0; c < CIN; c++) {
            float v = b2f(xp[c * HW]);
            int r = c * HD + d0;
            #pragma unroll
            for (int j = 0; j < 4; j++) {
                af[j] = fmaf(v, Wf[r + j], af[j]);
                ai[j] = fmaf(v, Wi[r + j], ai[j]);
                ag[j] = fmaf(v, Wc[r + j], ag[j]);
                ao[j] = fmaf(v, Wo[r + j], ao[j]);
            }
        }
    }
    if (!first) {
        #pragma unroll 2
        for (int c = 0; c < HD; c++) {
            float v = hp[c * HW];
            int r = (CIN + c) * HD + d0;
            #pragma unroll
            for (int j = 0; j < 4; j++) {
                af[j] = fmaf(v, Wf[r + j], af[j]);
                ai[j] = fmaf(v, Wi[r + j], ai[j]);
                ag[j] = fmaf(v, Wc[r + j], ag[j]);
                ao[j] = fmaf(v, Wo[r + j], ao[j]);
            }
        }
    }
    #pragma unroll
    for (int j = 0; j < 4; j++) {
        int d = d0 + j;
        float fg = sigmf_(af[j] + bfv[d]);
        float ig = sigmf_(ai[j] + biv[d]);
        float gg = tanhf_(ag[j] + bcv[d]);
        float og = sigmf_(ao[j] + bov[d]);
        int off = (b * HD + d) * HW + hw;
        float cp = first ? 0.0f : cst[off];
        float cn = fmaf(cp, fg, ig * gg);
        cst[off]  = cn;
        hout[off] = tanhf_(cn) * og;
    }
}

// ---------------------------------------------------------------------------
// decoder step: 3 fused conv3x3 gates + linear o-gate + LSTM update
// grid (16, 24, 8). border handling: clamped address + value mask (no OOB).
// ---------------------------------------------------------------------------
__global__ __launch_bounds__(256) void dec_step_k(
    const void* __restrict__ x, int t,
    const float* __restrict__ hin, float* __restrict__ hout, float* __restrict__ cst,
    const float* __restrict__ Kf, const float* __restrict__ Ki, const float* __restrict__ Kc,
    const float* __restrict__ bfv, const float* __restrict__ biv, const float* __restrict__ bcv,
    const float* __restrict__ Wo, const float* __restrict__ bov,
    const int* __restrict__ flag)
{
    const int f32 = *flag;
    const int hw = blockIdx.x * 256 + threadIdx.x;
    const int d0 = blockIdx.y * 4;
    const int b  = blockIdx.z;
    const int yy = hw >> 6, xx = hw & 63;

    int  nofs[9];
    bool nval[9];
    #pragma unroll
    for (int dy = -1; dy <= 1; dy++) {
        #pragma unroll
        for (int dx = -1; dx <= 1; dx++) {
            int k = (dy + 1) * 3 + (dx + 1);
            int y2 = yy + dy, x2 = xx + dx;
            bool v = ((unsigned)y2 < 64u) && ((unsigned)x2 < 64u);
            int y2c = v ? y2 : yy;
            int x2c = v ? x2 : xx;
            nofs[k] = y2c * WIMG + x2c;
            nval[k] = v;
        }
    }

    const long xbo = ((long)(b * T_ + t) * COUT) * HW;
    const float* hb = hin + (b * HD) * HW;

    float af[4] = {0,0,0,0}, ai[4] = {0,0,0,0}, ag[4] = {0,0,0,0}, ao[4] = {0,0,0,0};

    // segment 1: x_t channels, weight rows 0..7
    #pragma unroll 1
    for (int c = 0; c < COUT; c++) {
        float v[9];
        if (f32) {
            const float* xb = (const float*)x + xbo;
            #pragma unroll
            for (int k = 0; k < 9; k++) {
                float t0 = xb[c * HW + nofs[k]];
                v[k] = nval[k] ? t0 : 0.0f;
            }
        } else {
            const bf16* xb = (const bf16*)x + xbo;
            #pragma unroll
            for (int k = 0; k < 9; k++) {
                float t0 = b2f(xb[c * HW + nofs[k]]);
                v[k] = nval[k] ? t0 : 0.0f;
            }
        }
        #pragma unroll
        for (int j = 0; j < 4; j++) {
            const float* kf = Kf + ((d0 + j) * CD + c) * 9;
            const float* ki = Ki + ((d0 + j) * CD + c) * 9;
            const float* kc = Kc + ((d0 + j) * CD + c) * 9;
            #pragma unroll
            for (int k = 0; k < 9; k++) {
                af[j] = fmaf(v[k], kf[k], af[j]);
                ai[j] = fmaf(v[k], ki[k], ai[j]);
                ag[j] = fmaf(v[k], kc[k], ag[j]);
            }
            ao[j] = fmaf(v[4], Wo[c * HD + d0 + j], ao[j]);
        }
    }
    // segment 2: h channels (fp32 state), weight rows 8..103
    #pragma unroll 1
    for (int c = 0; c < HD; c++) {
        float v[9];
        #pragma unroll
        for (int k = 0; k < 9; k++) {
            float t0 = hb[c * HW + nofs[k]];
            v[k] = nval[k] ? t0 : 0.0f;
        }
        int cw = c + COUT;
        #pragma unroll
        for (int j = 0; j < 4; j++) {
            const float* kf = Kf + ((d0 + j) * CD + cw) * 9;
            const float* ki = Ki + ((d0 + j) * CD + cw) * 9;
            const float* kc = Kc + ((d0 + j) * CD + cw) * 9;
            #pragma unroll
            for (int k = 0; k < 9; k++) {
                af[j] = fmaf(v[k], kf[k], af[j]);
                ai[j] = fmaf(v[k], ki[k], ai[j]);
                ag[j] = fmaf(v[k], kc[k], ag[j]);
            }
            ao[j] = fmaf(v[4], Wo[cw * HD + d0 + j], ao[j]);
        }
    }

    #pragma unroll
    for (int j = 0; j < 4; j++) {
        int d = d0 + j;
        float fg = sigmf_(af[j] + bfv[d]);
        float ig = sigmf_(ai[j] + biv[d]);
        float gg = tanhf_(ag[j] + bcv[d]);
        float og = sigmf_(ao[j] + bov[d]);
        int off = (b * HD + d) * HW + hw;
        float cn = fmaf(cst[off], fg, ig * gg);
        cst[off]  = cn;
        hout[off] = tanhf_(cn) * og;
    }
}

// ---------------------------------------------------------------------------
// output head: conv3x3 with pre-combined K2 (96ch -> 8ch), dtype-flag store
// grid (16, 8): hw-tile, batch
// ---------------------------------------------------------------------------
__global__ __launch_bounds__(256) void out_step_k(
    const float* __restrict__ h, const float* __restrict__ K2, const float* __restrict__ b2,
    void* __restrict__ out, int t, const int* __restrict__ flag)
{
    const int f32 = *flag;
    const int hw = blockIdx.x * 256 + threadIdx.x;
    const int b  = blockIdx.y;
    const int yy = hw >> 6, xx = hw & 63;

    int  nofs[9];
    bool nval[9];
    #pragma unroll
    for (int dy = -1; dy <= 1; dy++) {
        #pragma unroll
        for (int dx = -1; dx <= 1; dx++) {
            int k = (dy + 1) * 3 + (dx + 1);
            int y2 = yy + dy, x2 = xx + dx;
            bool v = ((unsigned)y2 < 64u) && ((unsigned)x2 < 64u);
            int y2c = v ? y2 : yy;
            int x2c = v ? x2 : xx;
            nofs[k] = y2c * WIMG + x2c;
            nval[k] = v;
        }
    }

    const float* hb = h + (b * HD) * HW;
    float acc[8] = {0,0,0,0,0,0,0,0};

    #pragma unroll 1
    for (int c = 0; c < HD; c++) {
        float v[9];
        #pragma unroll
        for (int k = 0; k < 9; k++) {
            float t0 = hb[c * HW + nofs[k]];
            v[k] = nval[k] ? t0 : 0.0f;
        }
        #pragma unroll
        for (int k = 0; k < 9; k++) {
            const float* kk = K2 + (c * 9 + k) * COUT;
            #pragma unroll
            for (int o = 0; o < 8; o++)
                acc[o] = fmaf(v[k], kk[o], acc[o]);
        }
    }

    long ob = ((long)(b * T_ + t) * COUT) * HW + hw;
    if (f32) {
        float* op = (float*)out;
        #pragma unroll
        for (int o = 0; o < 8; o++)
            op[ob + o * HW] = acc[o] + b2[o];
    } else {
        bf16* op = (bf16*)out;
        #pragma unroll
        for (int o = 0; o < 8; o++)
            op[ob + o * HW] = __float2bfloat16(acc[o] + b2[o]);
    }
}

// ---------------------------------------------------------------------------
extern "C" void kernel_launch(void* const* d_in, const int* in_sizes, int n_in,
                              void* d_out, int out_size, void* d_ws, size_t ws_size,
                              hipStream_t stream)
{
    const void* enc_in = d_in[0];
    const void* dec_in = d_in[1];
    const void* eWf = d_in[2];  const void* ebf = d_in[3];
    const void* eWi = d_in[4];  const void* ebi = d_in[5];
    const void* eWc = d_in[6];  const void* ebc = d_in[7];
    const void* eWo = d_in[8];  const void* ebo = d_in[9];
    const void* dKf = d_in[10]; const void* dbf = d_in[11];
    const void* dKi = d_in[12]; const void* dbi = d_in[13];
    const void* dKc = d_in[14]; const void* dbc = d_in[15];
    const void* dWo = d_in[16]; const void* dbo = d_in[17];
    const void* oK  = d_in[18]; const void* obv = d_in[19];
    const void* lW  = d_in[20]; const void* lb  = d_in[21];

    int* flag = (int*)d_ws;
    float* ws = (float*)d_ws + 16;

    const int S = B_ * HD * HW;         // 3,145,728 floats per state buffer
    float* hA = ws;
    float* hB = hA + S;
    float* cS = hB + S;
    float* Wbase = cS + S;
    float* Wf   = Wbase;
    float* Wi   = Wf + 10752;
    float* Wc   = Wi + 10752;
    float* Wo   = Wc + 10752;
    float* bfv  = Wo + 10752;
    float* biv  = bfv + 96;
    float* bcv  = biv + 96;
    float* bov  = bcv + 96;
    float* Kf   = bov + 96;
    float* Ki   = Kf + 89856;
    float* Kc   = Ki + 89856;
    float* dbfv = Kc + 89856;
    float* dbiv = dbfv + 96;
    float* dbcv = dbiv + 96;
    float* dWof = dbcv + 96;
    float* dbov = dWof + 9984;
    float* K2   = dbov + 96;
    float* b2   = K2 + 6912;

    detect_k<<<dim3(1), dim3(64), 0, stream>>>(eWf, flag);
    prep_k<<<dim3(1263), dim3(256), 0, stream>>>(
        eWf, eWi, eWc, eWo, ebf, ebi, ebc, ebo,
        dKf, dKi, dKc, dbf, dbi, dbc, dWo, dbo, Wbase, flag);
    combine_k<<<dim3(4), dim3(256), 0, stream>>>(oK, obv, lW, lb, K2, b2, flag);

    float* hin = hA;
    float* hout = hB;
    for (int t = 0; t < T_; t++) {
        enc_step_k<<<dim3(16, 24, B_), dim3(256), 0, stream>>>(
            enc_in, t, hin, hout, cS,
            Wf, Wi, Wc, Wo, bfv, biv, bcv, bov, (t == 0) ? 1 : 0, flag);
        float* tmp = hin; hin = hout; hout = tmp;
    }
    for (int t = 0; t < T_; t++) {
        dec_step_k<<<dim3(16, 24, B_), dim3(256), 0, stream>>>(
            dec_in, t, hin, hout, cS,
            Kf, Ki, Kc, dbfv, dbiv, dbcv, dWof, dbov, flag);
        float* tmp = hin; hin = hout; hout = tmp;
        out_step_k<<<dim3(16, B_), dim3(256), 0, stream>>>(hin, K2, b2, d_out, t, flag);
    }
}